// Round 3
// baseline (340.061 us; speedup 1.0000x reference)
//
#include <hip/hip_runtime.h>

// Problem constants (fixed by the reference harness).
#define BB 64
#define SS 2048
#define DD 256
#define NSPLIT 32
#define S_PER (SS / NSPLIT)  // 64 rows of S per partial block

#define FLT_BIG 3.4028234e38f

// ---------------------------------------------------------------------------
// Single fused kernel. Block = (split, b). Each thread owns a float4 slice of
// D and accumulates 5 stats over 16 s-rows in registers (one wave load = one
// contiguous 1 KiB D-row, 16 B/lane coalescing optimum). Cross-wave combine
// in LDS, partials to global, then the LAST block to finish for doc b (device
// -scope atomic counter) combines the 32 split-partials and writes the 1024
// output elements of that doc. Saves a dispatch + a 10.5 MB partial re-read
// vs the two-kernel version.
// ---------------------------------------------------------------------------
__global__ __launch_bounds__(256) void fused_kernel(
    const int* __restrict__ chunk, const float* __restrict__ enc,
    const float* __restrict__ idf, float* __restrict__ pswe,
    float* __restrict__ pse, float* __restrict__ pse2,
    float* __restrict__ pmx, float* __restrict__ pmn,
    float* __restrict__ pws, unsigned int* __restrict__ cnt,
    float* __restrict__ out) {
  int split = blockIdx.x;
  int b = blockIdx.y;
  int tid = threadIdx.x;
  int dg = tid & 63;
  int ssub = tid >> 6;
  int s0 = split * S_PER;

  // Stage this block's 64 idf weights into LDS (one gather per row).
  __shared__ float sw[S_PER];
  if (tid < S_PER) sw[tid] = idf[chunk[b * SS + s0 + tid]];
  __syncthreads();

  // Wave 0: shuffle-reduce the 64 staged weights -> per-split wsum partial.
  if (tid < 64) {
    float w = sw[tid];
#pragma unroll
    for (int off = 32; off > 0; off >>= 1) w += __shfl_down(w, off, 64);
    if (tid == 0) pws[b * NSPLIT + split] = w;
  }

  float swe[4] = {0.f, 0.f, 0.f, 0.f};
  float se[4] = {0.f, 0.f, 0.f, 0.f};
  float se2[4] = {0.f, 0.f, 0.f, 0.f};
  float mx[4], mn[4];
#pragma unroll
  for (int k = 0; k < 4; k++) {
    mx[k] = -FLT_BIG;
    mn[k] = FLT_BIG;
  }

  const float* base = enc + ((size_t)(b * SS + s0)) * DD + (size_t)dg * 4;
#pragma unroll 8
  for (int i = 0; i < S_PER / 4; i++) {
    int srel = ssub + 4 * i;  // wave-uniform
    float w = sw[srel];       // LDS broadcast (free)
    float4 e = *(const float4*)(base + (size_t)srel * DD);
    float ev[4] = {e.x, e.y, e.z, e.w};
#pragma unroll
    for (int k = 0; k < 4; k++) {
      swe[k] = fmaf(w, ev[k], swe[k]);
      se[k] += ev[k];
      se2[k] = fmaf(ev[k], ev[k], se2[k]);
      mx[k] = fmaxf(mx[k], ev[k]);
      mn[k] = fminf(mn[k], ev[k]);
    }
  }

  // Cross-wave (ssub) combine in LDS: 5 stats x 4 waves x 256 d = 20 KiB.
  __shared__ float red[5][4][DD];
#pragma unroll
  for (int k = 0; k < 4; k++) {
    red[0][ssub][dg * 4 + k] = swe[k];
    red[1][ssub][dg * 4 + k] = se[k];
    red[2][ssub][dg * 4 + k] = se2[k];
    red[3][ssub][dg * 4 + k] = mx[k];
    red[4][ssub][dg * 4 + k] = mn[k];
  }
  __syncthreads();

  int d = tid;  // one partial column per thread, coalesced stores
  size_t gbase = ((size_t)b * NSPLIT + split) * DD + d;
  pswe[gbase] = (red[0][0][d] + red[0][1][d]) + (red[0][2][d] + red[0][3][d]);
  pse[gbase] = (red[1][0][d] + red[1][1][d]) + (red[1][2][d] + red[1][3][d]);
  pse2[gbase] = (red[2][0][d] + red[2][1][d]) + (red[2][2][d] + red[2][3][d]);
  pmx[gbase] = fmaxf(fmaxf(red[3][0][d], red[3][1][d]),
                     fmaxf(red[3][2][d], red[3][3][d]));
  pmn[gbase] = fminf(fminf(red[4][0][d], red[4][1][d]),
                     fminf(red[4][2][d], red[4][3][d]));

  // ---- last-block-arrives combine for doc b ----
  __shared__ int sIsLast;
  __syncthreads();  // drains all waves' partial stores (vmcnt(0) at barrier)
  if (tid == 0) {
    __threadfence();  // release: make this block's partials device-visible
    unsigned int old = atomicAdd(&cnt[b], 1u);  // device-scope by default
    sIsLast = (old == NSPLIT - 1);
  }
  __syncthreads();
  if (!sIsLast) return;
  __threadfence();  // acquire: see all other blocks' partials

  float cswe = 0.f, cse = 0.f, cse2 = 0.f;
  float cmx = -FLT_BIG, cmn = FLT_BIG;
  float wtot = 0.f;
#pragma unroll 4
  for (int sp = 0; sp < NSPLIT; sp++) {
    size_t idx = ((size_t)b * NSPLIT + sp) * DD + d;
    cswe += pswe[idx];
    cse += pse[idx];
    cse2 += pse2[idx];
    cmx = fmaxf(cmx, pmx[idx]);
    cmn = fminf(cmn, pmn[idx]);
    wtot += pws[b * NSPLIT + sp];  // uniform address -> broadcast load
  }

  float mu = cse / (float)SS;
  float stdv =
      sqrtf(fmaxf((cse2 - (float)SS * mu * mu) / (float)(SS - 1), 0.f));
  size_t ob = (size_t)b * 4 * DD;
  out[ob + d] = cswe / wtot;
  out[ob + DD + d] = cmx;
  out[ob + 2 * DD + d] = cmn;
  out[ob + 3 * DD + d] = stdv;
}

extern "C" void kernel_launch(void* const* d_in, const int* in_sizes, int n_in,
                              void* d_out, int out_size, void* d_ws,
                              size_t ws_size, hipStream_t stream) {
  const int* chunk = (const int*)d_in[0];
  const float* enc = (const float*)d_in[1];
  const float* idf = (const float*)d_in[2];
  float* out = (float*)d_out;

  float* ws = (float*)d_ws;
  size_t n = (size_t)BB * NSPLIT * DD;  // 524288 floats per stat array
  float* pswe = ws;
  float* pse = ws + n;
  float* pse2 = ws + 2 * n;
  float* pmx = ws + 3 * n;
  float* pmn = ws + 4 * n;
  float* pws = ws + 5 * n;                      // 2048 floats
  unsigned int* cnt = (unsigned int*)(ws + 5 * n + 4096);  // 64 uints

  // ws is poisoned 0xAA before every launch: zero the doc counters (256 B).
  hipMemsetAsync(cnt, 0, BB * sizeof(unsigned int), stream);

  fused_kernel<<<dim3(NSPLIT, BB), 256, 0, stream>>>(
      chunk, enc, idf, pswe, pse, pse2, pmx, pmn, pws, cnt, out);
}

// Round 4
// 199.588 us; speedup vs baseline: 1.7038x; 1.7038x over previous
//
#include <hip/hip_runtime.h>

// Problem constants (fixed by the reference harness).
#define BB 64
#define SS 2048
#define DD 256
#define NQ 4          // D-quarters; one block per (doc, quarter)
#define DQ (DD / NQ)  // 64 columns per block
#define NT 1024       // threads per block (16 waves)
#define NW (NT / 64)

#define FLT_BIG 3.4028234e38f

// ---------------------------------------------------------------------------
// One block = (quarter dq, doc b). 1024 threads: d4 = tid&15 picks a float4
// column within the quarter, srow = tid>>4 in [0,64) staggers rows; thread
// loops s = srow + 64k (32 iters, unroll 8 -> 8 KiB/wave in flight). Each
// wave-load covers 4 rows x 256 B contiguous segments. All five stats are
// finished inside the block: shuffle-combine the 4 row-groups per wave, one
// LDS combine across 16 waves, 64 threads write the quarter's 256 outputs.
// Zero inter-block communication (R3's device-fence pattern cost 3x).
// ---------------------------------------------------------------------------
__global__ __launch_bounds__(NT) void fused_kernel(
    const int* __restrict__ chunk, const float* __restrict__ enc,
    const float* __restrict__ idf, float* __restrict__ out) {
  const int dq = blockIdx.x;
  const int b = blockIdx.y;
  const int tid = threadIdx.x;
  const int lane = tid & 63;
  const int wid = tid >> 6;
  const int d4 = tid & 15;   // float4 column within quarter
  const int srow = tid >> 4; // 0..63

  __shared__ float sw[SS];          // 8 KiB: the doc's idf weights
  __shared__ float warr[NW];        // per-wave wsum partials
  __shared__ float red[NW][16][20]; // 20 KiB: cross-wave stat combine

  // Stage the doc's 2048 idf weights (2 gathers/thread); fold the local
  // wsum reduction into the same pass via a wave shuffle reduce.
  float w0 = idf[chunk[b * SS + tid]];
  float w1 = idf[chunk[b * SS + NT + tid]];
  sw[tid] = w0;
  sw[NT + tid] = w1;
  float wp = w0 + w1;
#pragma unroll
  for (int off = 32; off > 0; off >>= 1) wp += __shfl_down(wp, off, 64);
  if (lane == 0) warr[wid] = wp;
  __syncthreads();

  float swe[4] = {0.f, 0.f, 0.f, 0.f};
  float se[4] = {0.f, 0.f, 0.f, 0.f};
  float se2[4] = {0.f, 0.f, 0.f, 0.f};
  float mx[4], mn[4];
#pragma unroll
  for (int k = 0; k < 4; k++) {
    mx[k] = -FLT_BIG;
    mn[k] = FLT_BIG;
  }

  const float* base = enc + ((size_t)b * SS) * DD + dq * DQ + d4 * 4;
#pragma unroll 8
  for (int k = 0; k < SS / 64; k++) {
    int s = srow + 64 * k;
    float w = sw[s];  // 4 distinct consecutive addrs per wave: conflict-free
    float4 e = *(const float4*)(base + (size_t)s * DD);
    float ev[4] = {e.x, e.y, e.z, e.w};
#pragma unroll
    for (int j = 0; j < 4; j++) {
      swe[j] = fmaf(w, ev[j], swe[j]);
      se[j] += ev[j];
      se2[j] = fmaf(ev[j], ev[j], se2[j]);
      mx[j] = fmaxf(mx[j], ev[j]);
      mn[j] = fminf(mn[j], ev[j]);
    }
  }

  // Combine the 4 srow-groups within each wave (lanes l, l^16, l^32, l^48
  // share the same d4). Butterfly over xor 32, 16.
#pragma unroll
  for (int j = 0; j < 4; j++) {
    swe[j] += __shfl_xor(swe[j], 32, 64);
    swe[j] += __shfl_xor(swe[j], 16, 64);
    se[j] += __shfl_xor(se[j], 32, 64);
    se[j] += __shfl_xor(se[j], 16, 64);
    se2[j] += __shfl_xor(se2[j], 32, 64);
    se2[j] += __shfl_xor(se2[j], 16, 64);
    mx[j] = fmaxf(mx[j], __shfl_xor(mx[j], 32, 64));
    mx[j] = fmaxf(mx[j], __shfl_xor(mx[j], 16, 64));
    mn[j] = fminf(mn[j], __shfl_xor(mn[j], 32, 64));
    mn[j] = fminf(mn[j], __shfl_xor(mn[j], 16, 64));
  }
  if (lane < 16) {
    float* r = red[wid][lane];
#pragma unroll
    for (int j = 0; j < 4; j++) {
      r[j] = swe[j];
      r[4 + j] = se[j];
      r[8 + j] = se2[j];
      r[12 + j] = mx[j];
      r[16 + j] = mn[j];
    }
  }
  __syncthreads();

  // 64 threads finish the quarter: column c -> (float4 f4, component comp).
  if (tid < DQ) {
    int f4 = tid >> 2, comp = tid & 3;
    float cswe = 0.f, cse = 0.f, cse2 = 0.f, wtot = 0.f;
    float cmx = -FLT_BIG, cmn = FLT_BIG;
#pragma unroll
    for (int wv = 0; wv < NW; wv++) {
      const float* r = red[wv][f4];
      cswe += r[comp];
      cse += r[4 + comp];
      cse2 += r[8 + comp];
      cmx = fmaxf(cmx, r[12 + comp]);
      cmn = fminf(cmn, r[16 + comp]);
      wtot += warr[wv];
    }
    float mu = cse / (float)SS;
    float stdv =
        sqrtf(fmaxf((cse2 - (float)SS * mu * mu) / (float)(SS - 1), 0.f));
    int d = dq * DQ + tid;
    size_t ob = (size_t)b * 4 * DD;
    out[ob + d] = cswe / wtot;
    out[ob + DD + d] = cmx;
    out[ob + 2 * DD + d] = cmn;
    out[ob + 3 * DD + d] = stdv;
  }
}

extern "C" void kernel_launch(void* const* d_in, const int* in_sizes, int n_in,
                              void* d_out, int out_size, void* d_ws,
                              size_t ws_size, hipStream_t stream) {
  const int* chunk = (const int*)d_in[0];
  const float* enc = (const float*)d_in[1];
  const float* idf = (const float*)d_in[2];
  float* out = (float*)d_out;

  fused_kernel<<<dim3(NQ, BB), NT, 0, stream>>>(chunk, enc, idf, out);
}